// Round 5
// baseline (1143.341 us; speedup 1.0000x reference)
//
#include <hip/hip_runtime.h>
#include <math.h>

#define NB 8
#define NV 201
#define ND 256
#define NPIX (NB*NV*NV)        // 323208 (full pixel count; BN normalizer)
#define TRI  (NV*(NV+1)/2)     // 20301 upper-triangle pixels per batch (i<=j)
#define NSYM (NB*TRI)          // 162408 stored rows in symmetric mode
#define KSEL 100
#define BN_EPS 1e-5f
#define SLOPE 0.01f

__device__ __forceinline__ float lrelu(float v) { return v >= 0.f ? v : SLOPE * v; }

// ---- triangle index helpers (upper triangle incl. diagonal, row-major) ----
// base(i) = i*NV - i*(i-1)/2 ; row (i,j>=i) -> base(i) + (j-i)
__device__ __forceinline__ int tri_base(int i) { return i * NV - (i * (i - 1)) / 2; }
__device__ __forceinline__ void tri_decode(int s, int& b, int& i, int& j) {
    b = s / TRI;
    int t = s - b * TRI;
    float disc = (float)(403 * 403) - 8.0f * (float)t;   // (2*NV+1)^2 - 8t
    int ii = (int)((403.0f - sqrtf(disc)) * 0.5f);
    if (ii < 0) ii = 0;
    if (ii > NV - 1) ii = NV - 1;
    while (ii < NV - 1 && tri_base(ii + 1) <= t) ++ii;   // fixup (<=1 iter typ.)
    while (ii > 0 && tri_base(ii) > t) --ii;
    i = ii;
    j = t - tri_base(ii) + ii;
}

// ---- storage types ----
typedef _Float16 half4_t __attribute__((ext_vector_type(4)));
__device__ __forceinline__ float4 ld4(const float* p) { return *(const float4*)p; }
__device__ __forceinline__ float4 ld4(const _Float16* p) {
    half4_t u = *(const half4_t*)p;
    return make_float4((float)u.x, (float)u.y, (float)u.z, (float)u.w);
}
__device__ __forceinline__ void st4(float* p, float4 v) { *(float4*)p = v; }
__device__ __forceinline__ void st4(_Float16* p, float4 v) {
    half4_t u; u.x = (_Float16)v.x; u.y = (_Float16)v.y; u.z = (_Float16)v.z; u.w = (_Float16)v.w;
    *(half4_t*)p = u;
}

__global__ void zero_stats(double* p) { p[blockIdx.x * 256 + threadIdx.x] = 0.0; }

// Fused: [pairwise |xi-xj| gen (MODE 0) | BN+LeakyReLU on load (MODE 1)] -> 1x1 conv
// -> store + per-channel weighted sum/sumsq (DOUBLE atomics) for the next BN.
// SYM=1: rows are upper-triangle pixels; off-diagonal rows carry stats weight 2.
// SINGLE-OWNER tiles -> safe in-place (reads of own rows complete before writes).
template<int CIN, int COUT, int MODE, int BM, int NROW, int SYM,
         typename TIN, int SIN, typename TOUT, int SOUT>
__global__ __launch_bounds__(256)
void gemm_bn(const float* xin,               // MODE 0 source ([8,201,256] fp32)
             const TIN* in,                  // MODE 1 source (element stride SIN)
             const float* __restrict__ W,    // [COUT, CIN]
             const float* __restrict__ scale,
             const float* __restrict__ shift,
             TOUT* out,                      // element stride SOUT (may alias `in`)
             double* __restrict__ stat_sum,
             double* __restrict__ stat_sq)
{
    constexpr int BK  = 32;
    constexpr int RPT = BM / 16;     // rows per thread
    constexpr int CPT = COUT / 16;   // cols per thread
    __shared__ float As[BK][BM + 4];
    __shared__ float Bs[BK][COUT + 4];
    __shared__ float csum[COUT];
    __shared__ float csq[COUT];

    const int t  = threadIdx.x;
    const int tx = t & 15;
    const int ty = t >> 4;
    const int m0 = blockIdx.x * BM;

    float acc[RPT][CPT];
    #pragma unroll
    for (int i = 0; i < RPT; ++i)
        #pragma unroll
        for (int j = 0; j < CPT; ++j) acc[i][j] = 0.f;

    for (int kt = 0; kt < CIN; kt += BK) {
        // ---- stage A tile (transposed) ----
        #pragma unroll
        for (int f = 0; f < BM / 32; ++f) {
            int flat = t + 256 * f;          // BM rows x 8 float4
            int m    = flat >> 3;
            int kq   = flat & 7;
            int k    = kt + kq * 4;
            int pix  = m0 + m;
            float4 v = make_float4(0.f, 0.f, 0.f, 0.f);
            if (pix < NROW) {
                if constexpr (MODE == 0) {
                    int b, i, j;
                    if constexpr (SYM) {
                        tri_decode(pix, b, i, j);
                    } else {
                        b = pix / (NV * NV);
                        int r = pix - b * (NV * NV);
                        i = r / NV;
                        j = r - i * NV;
                    }
                    float4 xi = *(const float4*)(xin + ((size_t)(b * NV + i)) * ND + k);
                    float4 xj = *(const float4*)(xin + ((size_t)(b * NV + j)) * ND + k);
                    v = make_float4(fabsf(xi.x - xj.x), fabsf(xi.y - xj.y),
                                    fabsf(xi.z - xj.z), fabsf(xi.w - xj.w));
                } else {
                    float4 u  = ld4(in + (size_t)pix * SIN + k);
                    float4 sc = *(const float4*)(scale + k);
                    float4 sh = *(const float4*)(shift + k);
                    v.x = lrelu(fmaf(u.x, sc.x, sh.x));
                    v.y = lrelu(fmaf(u.y, sc.y, sh.y));
                    v.z = lrelu(fmaf(u.z, sc.z, sh.z));
                    v.w = lrelu(fmaf(u.w, sc.w, sh.w));
                }
            }
            As[kq * 4 + 0][m] = v.x;
            As[kq * 4 + 1][m] = v.y;
            As[kq * 4 + 2][m] = v.z;
            As[kq * 4 + 3][m] = v.w;
        }
        // ---- stage B tile (W transposed) ----
        #pragma unroll
        for (int f = 0; f < COUT / 32; ++f) {
            int flat = t + 256 * f;          // COUT rows x 8 float4
            int n    = flat >> 3;
            int kq   = flat & 7;
            int k    = kt + kq * 4;
            float4 w = *(const float4*)(W + (size_t)n * CIN + k);
            Bs[kq * 4 + 0][n] = w.x;
            Bs[kq * 4 + 1][n] = w.y;
            Bs[kq * 4 + 2][n] = w.z;
            Bs[kq * 4 + 3][n] = w.w;
        }
        __syncthreads();
        // ---- inner product ----
        #pragma unroll 4
        for (int k = 0; k < BK; ++k) {
            float a[RPT], b[CPT];
            #pragma unroll
            for (int rc = 0; rc < RPT / 4; ++rc)
                *(float4*)&a[rc * 4] = *(const float4*)&As[k][rc * 64 + ty * 4];
            #pragma unroll
            for (int cc = 0; cc < CPT / 4; ++cc)
                *(float4*)&b[cc * 4] = *(const float4*)&Bs[k][cc * 64 + tx * 4];
            #pragma unroll
            for (int i = 0; i < RPT; ++i)
                #pragma unroll
                for (int j = 0; j < CPT; ++j)
                    acc[i][j] = fmaf(a[i], b[j], acc[i][j]);
        }
        __syncthreads();
    }

    // ---- epilogue: stores + weighted per-channel stats (from unrounded fp32 acc) ----
    for (int n = t; n < COUT; n += 256) { csum[n] = 0.f; csq[n] = 0.f; }
    __syncthreads();

    float tsum[CPT], tsq[CPT];
    #pragma unroll
    for (int j = 0; j < CPT; ++j) { tsum[j] = 0.f; tsq[j] = 0.f; }

    #pragma unroll
    for (int i = 0; i < RPT; ++i) {
        int m   = (i >> 2) * 64 + ty * 4 + (i & 3);
        int pix = m0 + m;
        if (pix < NROW) {
            float w = 1.f;
            if constexpr (SYM) {
                int b, ii, jj;
                tri_decode(pix, b, ii, jj);
                w = (ii == jj) ? 1.f : 2.f;   // off-diagonal represents (i,j) and (j,i)
            }
            #pragma unroll
            for (int j = 0; j < CPT; ++j) {
                float v = acc[i][j];
                tsum[j] += w * v;
                tsq[j]  += w * v * v;
            }
            #pragma unroll
            for (int cc = 0; cc < CPT / 4; ++cc) {
                float4 v = make_float4(acc[i][cc * 4 + 0], acc[i][cc * 4 + 1],
                                       acc[i][cc * 4 + 2], acc[i][cc * 4 + 3]);
                st4(out + (size_t)pix * SOUT + cc * 64 + tx * 4, v);
            }
        }
    }
    #pragma unroll
    for (int j = 0; j < CPT; ++j) {
        int n = (j >> 2) * 64 + tx * 4 + (j & 3);
        atomicAdd(&csum[n], tsum[j]);
        atomicAdd(&csq[n],  tsq[j]);
    }
    __syncthreads();
    for (int n = t; n < COUT; n += 256) {
        atomicAdd(&stat_sum[n], (double)csum[n]);
        atomicAdd(&stat_sq[n],  (double)csq[n]);
    }
}

// double stats -> BN scale/shift (conv bias cancels exactly inside BatchNorm -> skipped)
__global__ void bn_finalize(const double* __restrict__ ssum, const double* __restrict__ ssq,
                            const float* __restrict__ g, const float* __restrict__ be,
                            float* __restrict__ scale, float* __restrict__ shift, int C)
{
    int c = threadIdx.x + blockIdx.x * blockDim.x;
    if (c < C) {
        double m = ssum[c] * (1.0 / NPIX);
        double v = ssq[c] * (1.0 / NPIX) - m * m;   // jnp.var, ddof=0
        float s = g[c] / sqrtf((float)v + BN_EPS);
        scale[c] = s;
        shift[c] = be[c] - (float)m * s;
    }
}

// BN3 + LeakyReLU + dot(w4) + b4 for every triangle row -> logit_tri[NSYM]
__global__ __launch_bounds__(256)
void logits_tri(const float* __restrict__ act,   // [NSYM, 256] (first 128 ch valid)
                const float* __restrict__ scale, const float* __restrict__ shift,
                const float* __restrict__ w4, const float* __restrict__ b4,
                float* __restrict__ lt)
{
    int s = blockIdx.x * 256 + threadIdx.x;
    if (s >= NSYM) return;
    const float* p = act + (size_t)s * 256;
    float acc = 0.f;
    #pragma unroll
    for (int c = 0; c < 128; c += 4) {
        float4 u  = ld4(p + c);
        float4 sc = *(const float4*)(scale + c);
        float4 sh = *(const float4*)(shift + c);
        float4 w  = *(const float4*)(w4 + c);
        acc += lrelu(fmaf(u.x, sc.x, sh.x)) * w.x;
        acc += lrelu(fmaf(u.y, sc.y, sh.y)) * w.y;
        acc += lrelu(fmaf(u.z, sc.z, sh.z)) * w.z;
        acc += lrelu(fmaf(u.w, sc.w, sh.w)) * w.w;
    }
    lt[s] = acc + b4[0];
}

// gather symmetric logits -> softmax over j -> top-K rank mask (stable tie-break)
__global__ __launch_bounds__(256)
void final_softmax_topk_sym(const float* __restrict__ lt, float* __restrict__ outp)
{
    __shared__ float sv[NV];
    __shared__ float red[256];
    const int row = blockIdx.x;                 // b*NV + i
    const int b   = row / NV;
    const int i   = row - b * NV;
    const int t   = threadIdx.x;

    float logit = -INFINITY;
    if (t < NV) {
        int jm = (i < t) ? i : t;
        int jM = (i < t) ? t : i;
        logit = lt[b * TRI + tri_base(jm) + (jM - jm)];
    }
    red[t] = logit;
    __syncthreads();
    #pragma unroll
    for (int off = 128; off > 0; off >>= 1) {
        if (t < off) red[t] = fmaxf(red[t], red[t + off]);
        __syncthreads();
    }
    float mx = red[0];
    __syncthreads();
    float e = (t < NV) ? expf(logit - mx) : 0.f;
    red[t] = e;
    __syncthreads();
    #pragma unroll
    for (int off = 128; off > 0; off >>= 1) {
        if (t < off) red[t] += red[t + off];
        __syncthreads();
    }
    float denom = red[0];
    __syncthreads();
    float val = e / denom;
    if (t < NV) sv[t] = val;
    __syncthreads();
    if (t < NV) {
        int rank = 0;
        for (int j = 0; j < NV; ++j) {
            float o = sv[j];
            rank += (o > val || (o == val && j < t)) ? 1 : 0;
        }
        outp[(size_t)row * NV + t] = (rank < KSEL) ? val : 0.f;
    }
}

// fallback head (full-pixel fp32 activations, stride S)
template<int S>
__global__ __launch_bounds__(256)
void final_softmax_topk_full(const float* a3,
                             const float* __restrict__ scale, const float* __restrict__ shift,
                             const float* __restrict__ w4, const float* __restrict__ b4,
                             float* __restrict__ outp)
{
    __shared__ float sv[NV];
    __shared__ float red[256];
    const int row = blockIdx.x;
    const int t   = threadIdx.x;
    float logit = -INFINITY;
    if (t < NV) {
        const float* p = a3 + ((size_t)row * NV + t) * S;
        float s = 0.f;
        #pragma unroll
        for (int c = 0; c < 128; c += 4) {
            float4 u  = ld4(p + c);
            float4 sc = *(const float4*)(scale + c);
            float4 sh = *(const float4*)(shift + c);
            float4 w  = *(const float4*)(w4 + c);
            s += lrelu(fmaf(u.x, sc.x, sh.x)) * w.x;
            s += lrelu(fmaf(u.y, sc.y, sh.y)) * w.y;
            s += lrelu(fmaf(u.z, sc.z, sh.z)) * w.z;
            s += lrelu(fmaf(u.w, sc.w, sh.w)) * w.w;
        }
        logit = s + b4[0];
    }
    red[t] = logit;
    __syncthreads();
    #pragma unroll
    for (int off = 128; off > 0; off >>= 1) {
        if (t < off) red[t] = fmaxf(red[t], red[t + off]);
        __syncthreads();
    }
    float mx = red[0];
    __syncthreads();
    float e = (t < NV) ? expf(logit - mx) : 0.f;
    red[t] = e;
    __syncthreads();
    #pragma unroll
    for (int off = 128; off > 0; off >>= 1) {
        if (t < off) red[t] += red[t + off];
        __syncthreads();
    }
    float denom = red[0];
    __syncthreads();
    float val = e / denom;
    if (t < NV) sv[t] = val;
    __syncthreads();
    if (t < NV) {
        int rank = 0;
        for (int j = 0; j < NV; ++j) {
            float o = sv[j];
            rank += (o > val || (o == val && j < t)) ? 1 : 0;
        }
        outp[(size_t)row * NV + t] = (rank < KSEL) ? val : 0.f;
    }
}

extern "C" void kernel_launch(void* const* d_in, const int* in_sizes, int n_in,
                              void* d_out, int out_size, void* d_ws, size_t ws_size,
                              hipStream_t stream)
{
    (void)in_sizes; (void)n_in; (void)out_size;

    const float* x   = (const float*)d_in[0];
    const float* w0  = (const float*)d_in[1];
    const float* g0  = (const float*)d_in[3];
    const float* be0 = (const float*)d_in[4];
    const float* w1  = (const float*)d_in[5];
    const float* g1  = (const float*)d_in[7];
    const float* be1 = (const float*)d_in[8];
    const float* w2  = (const float*)d_in[9];
    const float* g2  = (const float*)d_in[11];
    const float* be2 = (const float*)d_in[12];
    const float* w3  = (const float*)d_in[13];
    const float* g3  = (const float*)d_in[15];
    const float* be3 = (const float*)d_in[16];
    const float* w4  = (const float*)d_in[17];
    const float* b4  = (const float*)d_in[18];
    // b0..b3 unused: conv bias cancels exactly in the following BatchNorm.

    char* ws = (char*)d_ws;
    // layout: [double stats 16KB][scale/shift 8KB][logit_tri 650KB][activation buffer]
    double* D   = (double*)ws;                         // 4 stages x (sum[256]|sq[256])
    float*  F   = (float*)(ws + 16384);                // 4 stages x (scale[256]|shift[256])
    float*  lt  = (float*)(ws + 16384 + 8192);
    char*   bufc = ws + 16384 + 8192 + 655360;
    float*  outp = (float*)d_out;

    const size_t headBytes = 16384 + 8192 + 655360;
    const size_t needSym = headBytes + (size_t)NSYM * 256 * sizeof(float);     // ~167.0 MB
    const size_t needF16 = headBytes + (size_t)NPIX * 256 * sizeof(_Float16);  // ~166.1 MB

    zero_stats<<<8, 256, 0, stream>>>(D);

    if (ws_size >= needSym) {
        // ======== symmetric fp32 path: triangle rows only, all-fp32, double stats ========
        float* buf = (float*)bufc;
        const int gs64  = (NSYM + 63) / 64;     // 2538
        const int gs128 = (NSYM + 127) / 128;   // 1269

        gemm_bn<256, 256, 0, 64, NSYM, 1, float, 256, float, 256><<<gs64, 256, 0, stream>>>(
            x, (const float*)nullptr, w0, nullptr, nullptr, buf, D + 0, D + 256);
        bn_finalize<<<1, 256, 0, stream>>>(D + 0, D + 256, g0, be0, F + 0, F + 256, 256);

        gemm_bn<256, 256, 1, 64, NSYM, 1, float, 256, float, 256><<<gs64, 256, 0, stream>>>(
            nullptr, buf, w1, F + 0, F + 256, buf, D + 512, D + 768);
        bn_finalize<<<1, 256, 0, stream>>>(D + 512, D + 768, g1, be1, F + 512, F + 768, 256);

        gemm_bn<256, 128, 1, 128, NSYM, 1, float, 256, float, 256><<<gs128, 256, 0, stream>>>(
            nullptr, buf, w2, F + 512, F + 768, buf, D + 1024, D + 1280);
        bn_finalize<<<1, 256, 0, stream>>>(D + 1024, D + 1280, g2, be2, F + 1024, F + 1280, 128);

        gemm_bn<128, 128, 1, 128, NSYM, 1, float, 256, float, 256><<<gs128, 256, 0, stream>>>(
            nullptr, buf, w3, F + 1024, F + 1280, buf, D + 1536, D + 1792);
        bn_finalize<<<1, 256, 0, stream>>>(D + 1536, D + 1792, g3, be3, F + 1536, F + 1792, 128);

        logits_tri<<<(NSYM + 255) / 256, 256, 0, stream>>>(buf, F + 1536, F + 1792, w4, b4, lt);
        final_softmax_topk_sym<<<NB * NV, 256, 0, stream>>>(lt, outp);
    } else {
        // ======== fallback: full-pixel fp16(L0/L1)+fp32(L2/L3) (known-running) ========
        _Float16* bufH = (_Float16*)bufc;
        float*    buf3 = (float*)bufc;
        const int g64  = (NPIX + 63) / 64;
        const int g128 = (NPIX + 127) / 128;

        gemm_bn<256, 256, 0, 64, NPIX, 0, _Float16, 256, _Float16, 256><<<g64, 256, 0, stream>>>(
            x, (const _Float16*)nullptr, w0, nullptr, nullptr, bufH, D + 0, D + 256);
        bn_finalize<<<1, 256, 0, stream>>>(D + 0, D + 256, g0, be0, F + 0, F + 256, 256);

        gemm_bn<256, 256, 1, 64, NPIX, 0, _Float16, 256, _Float16, 256><<<g64, 256, 0, stream>>>(
            nullptr, bufH, w1, F + 0, F + 256, bufH, D + 512, D + 768);
        bn_finalize<<<1, 256, 0, stream>>>(D + 512, D + 768, g1, be1, F + 512, F + 768, 256);

        gemm_bn<256, 128, 1, 128, NPIX, 0, _Float16, 256, float, 128><<<g128, 256, 0, stream>>>(
            nullptr, bufH, w2, F + 512, F + 768, buf3, D + 1024, D + 1280);
        bn_finalize<<<1, 256, 0, stream>>>(D + 1024, D + 1280, g2, be2, F + 1024, F + 1280, 128);

        gemm_bn<128, 128, 1, 128, NPIX, 0, float, 128, float, 128><<<g128, 256, 0, stream>>>(
            nullptr, buf3, w3, F + 1024, F + 1280, buf3, D + 1536, D + 1792);
        bn_finalize<<<1, 256, 0, stream>>>(D + 1536, D + 1792, g3, be3, F + 1536, F + 1792, 128);

        final_softmax_topk_full<128><<<NB * NV, 256, 0, stream>>>(
            buf3, F + 1536, F + 1792, w4, b4, outp);
    }
}